// Round 1
// baseline (396.599 us; speedup 1.0000x reference)
//
#include <hip/hip_runtime.h>

// FELDMSTM: fused AutoCorrelationLayer(FourierBlock) + FFTDecompLayer
// B=8 N=2000 L=96 D=32 H=4 E=8 modes={1,4,5} kavg=25, float32 in/out.
//
// Math folding (exact):
//   q-bias drops (sum of cos/sin over full period = 0); k,v projections unused.
//   CS[d][m]   = sum_l x[l,d] * {cos,sin}(2*pi*m*l/96)        (forward basis)
//   X[c][m]    = sum_d Wq[c,d] * CS[d][m]   (Xre = Wq*Cx, Xim = -Wq*Sx)
//   O[h,o][m]  = sum_e X[h*8+e][m] * (W1 + i*W2)[n,h,e,o,m]
//   Z[d][m]    = sum_c Wo[d,c] * O[c][m]
//   new_x[l,d] = (1/48) * sum_m (Zre*cos - Zim*sin) + bo[d]
//   xr = x + new_x;  trend = 25-tap edge-padded mean;  res = xr - trend.
//
// R1 change vs 386us baseline: barrier count 12 -> 4. The tiny spectral
// mid-section (CS->X->O->Z, 192 floats/stage) is now computed by wave 0
// alone, wave-synchronously (in-order DS ops + wave_barrier; no block
// syncs). Removes 8 __syncthreads and all 96/192-active-lane phases.
// Scratch csb/xsb/osb live in the dead pp region of xT (LDS 34.3->31.2KB).

#define N_NODES 2000

__global__ __launch_bounds__(256, 4)
void fused_fourier_decomp(const float* __restrict__ x,
                          const float* __restrict__ Wq,
                          const float* __restrict__ Wo,
                          const float* __restrict__ bo,
                          const float* __restrict__ W1,
                          const float* __restrict__ W2,
                          float* __restrict__ out)
{
  // xT: xr staging, stride 97 -> bank (d + l) % 32, conflict-free column sweeps.
  // Aliases: pp = xT[0..1535] (phase-B partials; dead after wave0 reduce),
  //          sbuf = xT[1600..2111] (wave0 spectral scratch; dead before F).
  // xT is first written as xr in phase F, strictly after the last sbuf read.
  __shared__ __align__(16) float xT[32 * 97];
  __shared__ __align__(16) float basis[96 * 8];   // [l][0..2]=cos_m, [3..5]=sin_m
  __shared__ __align__(16) float Wq_s[32 * 33];   // [c][d], pad 33
  __shared__ __align__(16) float Wo_s[32 * 33];   // [dout][c], pad 33
  __shared__ __align__(16) float W1_s[768];       // (h,e,o,m) in-node layout
  __shared__ __align__(16) float W2_s[768];
  __shared__ __align__(16) float Z_s[32 * 8];     // [dout][0..2]=re, [3..5]=im
  __shared__ float bo_s[32];
  float* const pp = xT;                           // 1536 floats used
  float* const sbuf = xT + 1600;                  // 512 floats used

  const int t = threadIdx.x;
  const int bid = blockIdx.x;           // b*N + n
  const int n = bid % N_NODES;
  const size_t base = (size_t)bid * (96 * 32);

  const int d = t & 31;                 // owned channel / column
  const int g = t >> 5;                 // l-chunk 0..7 (12 rows each)
  const int l0 = g * 12;

  // ---- load x slice into registers: thread owns column d, rows l0..l0+11.
  // Lanes 0..31 read 128 contiguous bytes of row l0 (fully coalesced).
  float xv[12];
#pragma unroll
  for (int i = 0; i < 12; ++i)
    xv[i] = x[base + (size_t)(l0 + i) * 32 + d];

  // ---- stage weights (tiny; L2/L3-hot after first blocks)
  for (int i = t; i < 1024; i += 256) {
    Wq_s[(i >> 5) * 33 + (i & 31)] = Wq[i];
    Wo_s[(i >> 5) * 33 + (i & 31)] = Wo[i];
  }
  {
    const float* W1p = W1 + n * 768;
    const float* W2p = W2 + n * 768;
    for (int i = t; i < 768; i += 256) {
      W1_s[i] = W1p[i];
      W2_s[i] = W2p[i];
    }
  }
  if (t < 32) bo_s[t] = bo[t];

  // ---- cos/sin basis (exact integer angle reduction, precise sincos)
  if (t < 96) {
    const int modes[3] = {1, 4, 5};
#pragma unroll
    for (int m = 0; m < 3; ++m) {
      int r = (modes[m] * t) % 96;
      float ang = (float)r * (6.28318530717958647692f / 96.0f);
      float sv, cv;
      sincosf(ang, &sv, &cv);
      basis[t * 8 + m] = cv;
      basis[t * 8 + 3 + m] = sv;
    }
    basis[t * 8 + 6] = 0.0f;
    basis[t * 8 + 7] = 0.0f;
  }
  __syncthreads();   // barrier #1: staging + basis ready

  // ---- phase B: partial CS over own 12 rows (x from registers)
  {
    float a0 = 0.f, a1 = 0.f, a2 = 0.f, a3 = 0.f, a4 = 0.f, a5 = 0.f;
#pragma unroll
    for (int i = 0; i < 12; ++i) {
      const int l = l0 + i;
      const float4 b0 = *(const float4*)&basis[l * 8];
      const float2 b1 = *(const float2*)&basis[l * 8 + 4];
      const float v = xv[i];
      a0 = fmaf(v, b0.x, a0);
      a1 = fmaf(v, b0.y, a1);
      a2 = fmaf(v, b0.z, a2);
      a3 = fmaf(v, b0.w, a3);
      a4 = fmaf(v, b1.x, a4);
      a5 = fmaf(v, b1.y, a5);
    }
    pp[g * 192 + 0 * 32 + d] = a0;
    pp[g * 192 + 1 * 32 + d] = a1;
    pp[g * 192 + 2 * 32 + d] = a2;
    pp[g * 192 + 3 * 32 + d] = a3;
    pp[g * 192 + 4 * 32 + d] = a4;
    pp[g * 192 + 5 * 32 + d] = a5;
  }
  __syncthreads();   // barrier #2: pp ready

  // ---- wave-0 solo spectral section: reduce -> C -> D -> E (no block syncs;
  // DS ops from one wave complete in issue order; wave_barrier stops the
  // compiler from reordering across sub-phases).
  if (t < 64) {
    const int c = t & 31;           // channel this lane owns in each stage
    const int jj = t >> 5;          // 0: real half, 1: imag half
    float* const csb = sbuf;        // [32][8] raw CS (cos sums | sin sums)
    float* const xsb = sbuf + 256;  // [32][8] X (imag already sign-flipped)
    float* const osb = sbuf;        // reuse csb region after phase C

    // reduce: CS[d][j] = sum_g pp[g][j][d]   (g ascending = original order)
#pragma unroll
    for (int k = 0; k < 3; ++k) {
      const int j = jj * 3 + k;
      float s = 0.f;
#pragma unroll
      for (int gg = 0; gg < 8; ++gg) s += pp[gg * 192 + j * 32 + c];
      csb[c * 8 + j] = s;
    }
    __builtin_amdgcn_wave_barrier();

    // phase C: X = Wq * CS ; Xim picks up the rfft minus sign
    {
      float X0 = 0.f, X1 = 0.f, X2 = 0.f;
#pragma unroll
      for (int dd = 0; dd < 32; ++dd) {
        const float w = Wq_s[c * 33 + dd];
        const int cb = dd * 8 + jj * 3;
        X0 = fmaf(w, csb[cb + 0], X0);
        X1 = fmaf(w, csb[cb + 1], X1);
        X2 = fmaf(w, csb[cb + 2], X2);
      }
      const float sgn = jj ? -1.f : 1.f;
      xsb[c * 8 + jj * 3 + 0] = sgn * X0;
      xsb[c * 8 + jj * 3 + 1] = sgn * X1;
      xsb[c * 8 + jj * 3 + 2] = sgn * X2;
    }
    __builtin_amdgcn_wave_barrier();

    // phase D: per-head complex contraction over e (einsum bnhem,nheom).
    // jj=0 lanes produce Re(O[h,o][m]), jj=1 lanes produce Im(O[h,o][m]).
    {
      const int h = (t >> 3) & 3;
      const int o = t & 7;
      float od0 = 0.f, od1 = 0.f, od2 = 0.f;
#pragma unroll
      for (int e = 0; e < 8; ++e) {
        const int cp = h * 8 + e;
        const float4 xa = *(const float4*)&xsb[cp * 8];     // Xre0,Xre1,Xre2,Xim0
        const float2 xb = *(const float2*)&xsb[cp * 8 + 4]; // Xim1,Xim2
        const int wi = (cp * 8 + o) * 3;
        {  // m = 0
          const float w1 = W1_s[wi + 0], w2 = W2_s[wi + 0];
          const float a = jj ? w1 : -w2;   // coeff on Xim
          const float b = jj ? w2 : w1;    // coeff on Xre
          od0 = fmaf(xa.x, b, fmaf(xa.w, a, od0));
        }
        {  // m = 1
          const float w1 = W1_s[wi + 1], w2 = W2_s[wi + 1];
          const float a = jj ? w1 : -w2;
          const float b = jj ? w2 : w1;
          od1 = fmaf(xa.y, b, fmaf(xb.x, a, od1));
        }
        {  // m = 2
          const float w1 = W1_s[wi + 2], w2 = W2_s[wi + 2];
          const float a = jj ? w1 : -w2;
          const float b = jj ? w2 : w1;
          od2 = fmaf(xa.z, b, fmaf(xb.y, a, od2));
        }
      }
      const int cp = h * 8 + o;
      osb[cp * 8 + jj * 3 + 0] = od0;
      osb[cp * 8 + jj * 3 + 1] = od1;
      osb[cp * 8 + jj * 3 + 2] = od2;
    }
    __builtin_amdgcn_wave_barrier();

    // phase E: Z = Wo * O  (fold output projection into spectrum)
    {
      float z0 = 0.f, z1 = 0.f, z2 = 0.f;
#pragma unroll
      for (int cc = 0; cc < 32; ++cc) {
        const float w = Wo_s[c * 33 + cc];
        const int ob = cc * 8 + jj * 3;
        z0 = fmaf(w, osb[ob + 0], z0);
        z1 = fmaf(w, osb[ob + 1], z1);
        z2 = fmaf(w, osb[ob + 2], z2);
      }
      Z_s[c * 8 + jj * 3 + 0] = z0;
      Z_s[c * 8 + jj * 3 + 1] = z1;
      Z_s[c * 8 + jj * 3 + 2] = z2;
    }
  }
  __syncthreads();   // barrier #3: Z_s ready

  // ---- phase F: irfft synthesis + out-bias + residual -> xr (regs + LDS)
  float xr[12];
  {
    const float4 z0 = *(const float4*)&Z_s[d * 8];     // (re0,re1,re2,im0)
    const float2 z1 = *(const float2*)&Z_s[d * 8 + 4]; // (im1,im2)
    const float bov = bo_s[d];
#pragma unroll
    for (int i = 0; i < 12; ++i) {
      const int l = l0 + i;
      const float4 b0 = *(const float4*)&basis[l * 8];     // (c0,c1,c2,s0)
      const float2 b1 = *(const float2*)&basis[l * 8 + 4]; // (s1,s2)
      const float v = z0.x * b0.x + z0.y * b0.y + z0.z * b0.z
                    - z0.w * b0.w - z1.x * b1.x - z1.y * b1.y;
      const float r = fmaf(v, (1.0f / 48.0f), bov) + xv[i];
      xr[i] = r;
      xT[d * 97 + l] = r;
    }
  }
  __syncthreads();   // barrier #4: xT ready

  // ---- phase G: 25-tap edge-padded moving average (running window) + store
  {
    const float* col = &xT[d * 97];
    float lowv[12];
    float S = 0.f;
#pragma unroll
    for (int j = 0; j < 12; ++j) {          // below-window taps l0-12..l0-1 (clamped)
      int idx = l0 - 12 + j;
      idx = idx < 0 ? 0 : idx;
      lowv[j] = col[idx];
      S += lowv[j];
    }
#pragma unroll
    for (int i = 0; i < 12; ++i) S += xr[i]; // own rows l0..l0+11
    {
      int idx = l0 + 12;                     // top tap of first window
      idx = idx > 95 ? 95 : idx;
      S += col[idx];
    }
#pragma unroll
    for (int i = 0; i < 12; ++i) {
      const int l = l0 + i;
      const float res = xr[i] - S * (1.0f / 25.0f);
      out[base + (size_t)l * 32 + d] = res;
      // slide window: drop clamp(l-12), add clamp(l+13)
      int hi = l + 13;
      hi = hi > 95 ? 95 : hi;
      S += col[hi] - lowv[i];
    }
  }
}

extern "C" void kernel_launch(void* const* d_in, const int* in_sizes, int n_in,
                              void* d_out, int out_size, void* d_ws, size_t ws_size,
                              hipStream_t stream) {
  (void)n_in; (void)out_size; (void)d_ws; (void)ws_size;
  const float* x  = (const float*)d_in[0];
  const float* Wq = (const float*)d_in[1];
  // d_in[2]=bq (exactly cancelled), d_in[3..6]=Wk,bk,Wv,bv (unused by output)
  const float* Wo = (const float*)d_in[7];
  const float* bo = (const float*)d_in[8];
  const float* W1 = (const float*)d_in[9];
  const float* W2 = (const float*)d_in[10];
  float* out = (float*)d_out;

  const int blocks = in_sizes[0] / (96 * 32);  // B*N tiles of 96x32
  fused_fourier_decomp<<<blocks, 256, 0, stream>>>(x, Wq, Wo, bo, W1, W2, out);
}